// Round 7
// baseline (3683.886 us; speedup 1.0000x reference)
//
#include <hip/hip_runtime.h>
#include <hip/hip_bf16.h>
#include <stdint.h>

// BertBiLstmCrf: B=64 T=512 H=768 LH=384 L=12
// prep -> gemm_xp0 -> fused_rec(p) x16 -> fc_em -> viterbi
// fused_rec(p): XCD0 blocks run lstm phase p or exit; XCD1-7 blocks run gemm
// phase p+1 as 128 persistent workers x 3 tiles (throttled burst).
// lstm v7: W_hh fragments in REGISTERS, pinned with asm "+v" so the compiler
// cannot rematerialize them (R5's silent per-step reload) and doesn't read
// them from LDS every step (R6's 48 extra ds_read_b128/wave = ~1us/step).
// 153KB LDS union kept on purpose: forces 1 WG/CU -> 1 wave/SIMD -> 512-VGPR
// budget for the ~300-VGPR lstm state, and no co-located-worker skew.

#define NB 64
#define NT 512
#define NH 768
#define NLH 384
#define NPH 16
#define PS 32
#define NEGV -1000.0f

typedef __attribute__((ext_vector_type(4))) float f32x4;
typedef __attribute__((ext_vector_type(8))) short bf16x8;
typedef __attribute__((ext_vector_type(4))) unsigned int u32x4;
typedef unsigned short u16;
typedef unsigned int u32;

#define PSLOT ((size_t)PS * 3072 * 64)   // u16 elements per XPc phase buffer

__device__ __forceinline__ u16 f2bf(float f) {
  __hip_bfloat16 h = __float2bfloat16(f);
  return *reinterpret_cast<u16*>(&h);
}
__device__ __forceinline__ float bf2f(u16 u) {
  union { u32 i; float f; } v; v.i = ((u32)u) << 16; return v.f;
}
__device__ __forceinline__ u32 pack2(float a, float b) {
  return (u32)f2bf(a) | ((u32)f2bf(b) << 16);
}
__device__ __forceinline__ float bfx(uint2 v, int r) {
  u32 w = (r & 2) ? v.y : v.x;
  u16 h = (r & 1) ? (u16)(w >> 16) : (u16)(w & 0xffff);
  return bf2f(h);
}
__device__ __forceinline__ float sigm(float x) {
  x = fminf(fmaxf(x, -60.f), 60.f);
  return 1.0f / (1.0f + __expf(-x));
}
__device__ __forceinline__ float tanh_(float x) {
  x = fminf(fmaxf(x, -30.f), 30.f);
  return 2.0f / (1.0f + __expf(-2.0f * x)) - 1.0f;
}
__device__ __forceinline__ int xcc_id() {
  u32 v;
  asm volatile("s_getreg_b32 %0, hwreg(HW_REG_XCC_ID)" : "=s"(v));
  return (int)v;
}
__device__ __forceinline__ float rdlanef(float v, int lane) {
  union { float f; int i; } u; u.f = v;
  int r = __builtin_amdgcn_readlane(u.i, lane);
  union { int i; float f; } o; o.i = r; return o.f;
}

struct GemmSmem { u16 As[128][40]; u16 Bs[128][40]; };            //  20,480 B
struct LstmSmem {
  u16 hsm[64][392];            // h_{t-1} staged [b][k]             50,176 B
  u16 hxch[64][32];            // h_t repack scratch [b][jloc]       4,096 B
  u16 pad_1wg[49152];          // occupancy pad: forces 1 WG/CU     98,304 B
};
union SmemU { GemmSmem g; LstmSmem l; };

// ---- prep ------------------------------------------------------------------
__global__ __launch_bounds__(256) void prep_kernel(
    const float* bihf, const float* bhhf, const float* bihb, const float* bhhb,
    const float* h0, const float* c0, float* bias2, u16* hraw, float* cbuf,
    u32* flags, u32* claim) {
  int t = blockIdx.x * 256 + threadIdx.x;
  if (t < 1536) bias2[t] = bihf[t] + bhhf[t];
  else if (t < 3072) bias2[t] = bihb[t - 1536] + bhhb[t - 1536];
  if (t < 32) flags[t] = 0;
  if (t < 32) claim[t] = 0;                       // 16 lstm + 16 gemm claims
  if (t < 2 * NB * NLH) {
    hraw[t] = f2bf(h0[t]);   // slots 0,1 = dir 0,1 (parity 0), layout [b][j]
    int dir = t / 24576, r2 = t % 24576;
    int j = r2 / 64, b = r2 % 64;
    cbuf[t] = c0[(size_t)(dir * 64 + b) * 384 + j];  // cbuf[dir][j][b]
  }
}

// ---- gemm tile (device): XPout[(sl*3072 + n)*64 + b] for one 128x128 tile --
__device__ __forceinline__ void gemm_tile_dev(
    const float* __restrict__ A, const float* __restrict__ Wf,
    const float* __restrict__ Wb, const float* __restrict__ bias2,
    u16* __restrict__ XPout, int phaseG, int nb, int mb, GemmSmem& sm,
    int tid) {
  int dir = (nb >= 12) ? 1 : 0;
  const float* Bm = dir ? Wb : Wf;
  int n0g = nb * 128;
  int n0 = n0g - dir * 1536;
  int m0 = mb * 128;
  int tf0 = PS * phaseG, tb0 = (NT - 1) - PS * phaseG;
  int lane = tid & 63, wv = tid >> 6;
  int wm = (wv >> 1) * 64, wn = (wv & 1) * 64;
  int qr = lane & 15, qk8 = (lane >> 4) * 8, qm = (lane >> 4) * 4;

  f32x4 acc[4][4] = {};
  for (int kk = 0; kk < 768; kk += 32) {
    __syncthreads();
#pragma unroll
    for (int u = 0; u < 4; ++u) {
      int c = tid + u * 256;
      int row = c >> 3, q4 = (c & 7) * 4;
      int m = m0 + row;
      int sloc = m >> 6, b = m & 63;
      int t = dir ? (tb0 - sloc) : (tf0 + sloc);
      float4 av = *(const float4*)&A[(size_t)(b * NT + t) * 768 + kk + q4];
      float4 bv = *(const float4*)&Bm[(size_t)(n0 + row) * 768 + kk + q4];
      uint2 ap; ap.x = pack2(av.x, av.y); ap.y = pack2(av.z, av.w);
      uint2 bp; bp.x = pack2(bv.x, bv.y); bp.y = pack2(bv.z, bv.w);
      *(uint2*)&sm.As[row][q4] = ap;
      *(uint2*)&sm.Bs[row][q4] = bp;
    }
    __syncthreads();
    bf16x8 af[4], bfr[4];
#pragma unroll
    for (int i = 0; i < 4; ++i) af[i] = *(const bf16x8*)&sm.As[wm + i * 16 + qr][qk8];
#pragma unroll
    for (int j = 0; j < 4; ++j) bfr[j] = *(const bf16x8*)&sm.Bs[wn + j * 16 + qr][qk8];
#pragma unroll
    for (int i = 0; i < 4; ++i)
#pragma unroll
      for (int j = 0; j < 4; ++j)
        acc[i][j] = __builtin_amdgcn_mfma_f32_16x16x32_bf16(af[i], bfr[j], acc[i][j], 0, 0, 0);
  }
#pragma unroll
  for (int j = 0; j < 4; ++j) {
    int n = n0g + wn + j * 16 + qr;
    float bv = bias2[n];
#pragma unroll
    for (int i = 0; i < 4; ++i) {
      int mrel = wm + i * 16 + qm;           // 0..124 (r adds 0..3)
      int b0 = mrel & 63;
      int sl = mb * 2 + (mrel >> 6);         // 0..31
      uint2 pk;
      pk.x = pack2(acc[i][j][0] + bv, acc[i][j][1] + bv);
      pk.y = pack2(acc[i][j][2] + bv, acc[i][j][3] + bv);
      *(uint2*)&XPout[((size_t)sl * 3072 + n) * 64 + b0] = pk;
    }
  }
}

// ---- gemm_xp0: standalone gemm for phase 0 ----------------------------------
__global__ __launch_bounds__(256) void gemm_xp0(
    const float* __restrict__ A, const float* __restrict__ Wf,
    const float* __restrict__ Wb, const float* __restrict__ bias2,
    u16* __restrict__ XPc) {
  __shared__ GemmSmem sm;
  gemm_tile_dev(A, Wf, Wb, bias2, XPc, 0, blockIdx.x, blockIdx.y, sm,
                threadIdx.x);
}

// ---- fused_rec: lstm phase p (XCD0) || throttled gemm phase p+1 (XCD1-7) ----
__global__ __launch_bounds__(256, 1) void fused_rec(
    const float* __restrict__ Whhf, const float* __restrict__ Whhb,
    const float* __restrict__ A, const float* __restrict__ Wihf,
    const float* __restrict__ Wihb, const float* __restrict__ bias2,
    u16* __restrict__ XPc, u16* hraw, float* cbuf,
    u16* __restrict__ LOUT, u32* flags, u32* claim, int phase) {
  __shared__ SmemU sm;
  __shared__ int s_role;
  int tid = threadIdx.x;

  if (tid == 0) {
    int role = -1;
    if (xcc_id() == 0) {
      // XCD0: lstm worker or exit — lstm CUs never share with gemm
      u32 r = __hip_atomic_fetch_add(&claim[phase], 1u,
                                     __ATOMIC_RELAXED, __HIP_MEMORY_SCOPE_AGENT);
      if (r < 24u) role = (int)r;
    } else if (phase + 1 < NPH) {
      // XCD1-7: persistent gemm worker (128 x 3 tiles) or exit
      u32 g = __hip_atomic_fetch_add(&claim[16 + phase], 1u,
                                     __ATOMIC_RELAXED, __HIP_MEMORY_SCOPE_AGENT);
      if (g < 128u) role = 24 + (int)g;
    }
    s_role = role;
  }
  __syncthreads();
  int role = s_role;
  if (role < 0) return;

  if (role >= 24) {                               // ---- gemm role ----
    int g = role - 24;                            // 0..127
    u16* XPgemm = XPc + (size_t)((phase + 1) & 1) * PSLOT;
#pragma unroll 1
    for (int i = 0; i < 3; ++i) {                 // 3 tiles, serialized:
      int tile = g + 128 * i;                     // throttles burst BW ~3x
      int nb = tile % 24, mb = tile / 24;         // 24 x 16 tiles
      gemm_tile_dev(A, Wihf, Wihb, bias2, XPgemm, phase + 1, nb, mb, sm.g, tid);
    }
    return;
  }

  // ---- lstm role ----
  auto& hsm = sm.l.hsm;
  auto& hxch = sm.l.hxch;
  const u16* __restrict__ XPlstm = XPc + (size_t)(phase & 1) * PSLOT;

  int dir = role / 12, gidx = role % 12;
  int j0 = gidx * 32;
  int lane = tid & 63, wv = tid >> 6;
  int mgrp = wv >> 1, jt = wv & 1;
  int wm3 = mgrp * 32;
  int ll = lane & 15, qk8 = (lane >> 4) * 8, qm = (lane >> 4) * 4;
  int jloc = jt * 16 + ll, jg = j0 + jloc;
  const float* Whh = dir ? Whhb : Whhf;

  // W_hh fragments in registers: Bf[kk][g] covers rows g*384 + jg.
  // asm "+v" pin: value becomes opaque -> compiler CANNOT rematerialize
  // (R5 silently reloaded W every step at its 192-VGPR cap). At 1 WG/CU
  // (forced by 153KB LDS) each wave has the full 512-VGPR budget.
  bf16x8 Bf[12][4];
#pragma unroll
  for (int kk = 0; kk < 12; ++kk)
#pragma unroll
    for (int g = 0; g < 4; ++g) {
      const float* wp = &Whh[(size_t)(g * 384 + jg) * 384 + kk * 32 + qk8];
      float4 w0 = *(const float4*)wp;
      float4 w1 = *(const float4*)(wp + 4);
      union { u32 u[4]; bf16x8 v; } cv;
      cv.u[0] = pack2(w0.x, w0.y); cv.u[1] = pack2(w0.z, w0.w);
      cv.u[2] = pack2(w1.x, w1.y); cv.u[3] = pack2(w1.z, w1.w);
      Bf[kk][g] = cv.v;
      asm volatile("" : "+v"(Bf[kk][g]));   // pin in VGPRs
    }

  float cst[2][4];
#pragma unroll
  for (int mt = 0; mt < 2; ++mt)
    *(f32x4*)cst[mt] = *(const f32x4*)&cbuf[((size_t)dir * 384 + jg) * 64 + wm3 + mt * 16 + qm];

  int tf0 = PS * phase, tb0 = (NT - 1) - PS * phase;
  const size_t hslot = (size_t)NB * NLH;
  u32* myflag = &flags[dir * 16 + gidx];

  for (int s = 0; s < PS; ++s) {
    int stepidx = phase * PS + s;
    int t = dir ? (tb0 - s) : (tf0 + s);
    int pp = s & 1;                         // PS even -> parity continues
    const u16* hsrc = hraw + (size_t)(pp * 2 + dir) * hslot;
    u16* hdst = hraw + (size_t)((pp ^ 1) * 2 + dir) * hslot;

    // XP prefetch (top-of-step) — latency hides under h-stage+MFMA
    uint2 xpv[2][4];
    const u16* xpb = &XPlstm[(((size_t)s * 3072) + dir * 1536 + jg) * 64];
#pragma unroll
    for (int mt = 0; mt < 2; ++mt)
#pragma unroll
      for (int g = 0; g < 4; ++g)
        xpv[mt][g] = *(const uint2*)&xpb[(size_t)g * 384 * 64 + wm3 + mt * 16 + qm];

    // stage h_{t-1}: 3072 x 16B NONTEMPORAL loads (L1-bypass -> XCD0 L2)
#pragma unroll
    for (int i = 0; i < 12; ++i) {
      int u = tid + i * 256;
      int b = u / 48, c16 = u % 48;
      u32x4 v = __builtin_nontemporal_load(
          (const u32x4*)&hsrc[(size_t)b * 384 + c16 * 8]);
      *(u32x4*)&hsm[b][c16 * 8] = v;
    }
    __syncthreads();

    // gates = h @ W^T (A from hsm LDS, B from pinned registers)
    f32x4 acc[2][4] = {};
#pragma unroll
    for (int kk = 0; kk < 12; ++kk) {
      bf16x8 af0 = *(const bf16x8*)&hsm[wm3 + ll][kk * 32 + qk8];
      bf16x8 af1 = *(const bf16x8*)&hsm[wm3 + 16 + ll][kk * 32 + qk8];
#pragma unroll
      for (int g = 0; g < 4; ++g) {
        acc[0][g] = __builtin_amdgcn_mfma_f32_16x16x32_bf16(af0, Bf[kk][g], acc[0][g], 0, 0, 0);
        acc[1][g] = __builtin_amdgcn_mfma_f32_16x16x32_bf16(af1, Bf[kk][g], acc[1][g], 0, 0, 0);
      }
    }

    // combine i,f,g,o -> c,h  (LOUT stores issued here; drained by the two
    // barriers below, BEFORE the flag store -> poll sees clean vmcnt)
#pragma unroll
    for (int mt = 0; mt < 2; ++mt)
#pragma unroll
      for (int r = 0; r < 4; ++r) {
        int b = wm3 + mt * 16 + qm + r;
        float pi = acc[mt][0][r] + bfx(xpv[mt][0], r);
        float pf = acc[mt][1][r] + bfx(xpv[mt][1], r);
        float pg = acc[mt][2][r] + bfx(xpv[mt][2], r);
        float po = acc[mt][3][r] + bfx(xpv[mt][3], r);
        float ig = sigm(pi), fg = sigm(pf), gg = tanh_(pg), og = sigm(po);
        float cv = fg * cst[mt][r] + ig * gg;
        cst[mt][r] = cv;
        u16 hb = f2bf(og * tanh_(cv));
        hxch[b][jloc] = hb;
        LOUT[((size_t)b * NT + t) * 768 + dir * 384 + jg] = hb;
      }
    __syncthreads();

    // publish h_t slice: 256 x 16B plain write-through stores -> XCD0 L2
    {
      int b = tid >> 2, c = tid & 3;
      *(u32x4*)&hdst[(size_t)b * 384 + j0 + c * 8] = *(const u32x4*)&hxch[b][c * 8];
    }
    __syncthreads();  // vmcnt(0) drain: all h stores in L2 before flag store

    if (tid == 0)
      __hip_atomic_store(myflag, (u32)(stepidx + 1),
                         __ATOMIC_RELAXED, __HIP_MEMORY_SCOPE_WORKGROUP);
    if (wv == 0) {
      int spins = 0;
      while (true) {
        u32 v = 0xffffffffu;
        if (lane < 12)
          v = __builtin_nontemporal_load(&flags[dir * 16 + lane]);
        asm volatile("" ::: "memory");  // no CSE across poll iterations
        if (~__ballot(v > (u32)stepidx) == 0ull) break;
        __builtin_amdgcn_s_sleep(1);
        if (++spins > (1 << 14)) break;  // fail-fast liveness guard
      }
    }
    __syncthreads();
  }

  // persist c state
#pragma unroll
  for (int mt = 0; mt < 2; ++mt)
    *(f32x4*)&cbuf[((size_t)dir * 384 + jg) * 64 + wm3 + mt * 16 + qm] = *(f32x4*)cst[mt];
}

// ---- fc_em: emissions = LOUT @ fc_w^T + fc_b --------------------------------
__global__ __launch_bounds__(256) void fc_em(
    const u16* __restrict__ LOUT, const float* __restrict__ fcw,
    const float* __restrict__ fcb, float* __restrict__ em) {
  __shared__ float wsm[12][768];
  __shared__ float wbv[12];
  int tid = threadIdx.x;
  for (int i = tid; i < 12 * 768; i += 256) wsm[i / 768][i % 768] = fcw[i];
  if (tid < 12) wbv[tid] = fcb[tid];
  __syncthreads();
  int lane = tid & 63, wv = tid >> 6;
  for (int r = blockIdx.x * 4 + wv; r < NB * NT; r += gridDim.x * 4) {
    float x[12];
#pragma unroll
    for (int c = 0; c < 12; ++c) x[c] = bf2f(LOUT[(size_t)r * 768 + c * 64 + lane]);
    float sums[12];
#pragma unroll
    for (int l = 0; l < 12; ++l) {
      float pv = 0.f;
#pragma unroll
      for (int c = 0; c < 12; ++c) pv += x[c] * wsm[l][c * 64 + lane];
#pragma unroll
      for (int off = 32; off > 0; off >>= 1) pv += __shfl_xor(pv, off);
      sums[l] = pv + wbv[l];
    }
    if (lane == 0) {
#pragma unroll
      for (int l = 0; l < 12; ++l) em[(size_t)r * 12 + l] = sums[l];
    }
  }
}

// ---- viterbi v2: one block per batch, fully LDS-resident --------------------
__global__ __launch_bounds__(256) void viterbi_k(
    const float* __restrict__ em, const float* __restrict__ trans,
    const int* __restrict__ startp, float* __restrict__ outp) {
  __shared__ __align__(16) float feat_s[NT][12];    // 24576 B
  __shared__ unsigned char ptr_s[NT][12];           // 6144 B (rows 0..510 used)
  __shared__ int path_s[NT];                        // 2048 B
  int tid = threadIdx.x;
  int b = blockIdx.x;

  // stage emissions for this batch: 6144 floats = 1536 float4, coalesced
  {
    const float4* src = (const float4*)(em + (size_t)b * NT * 12);
    float4* dst = (float4*)&feat_s[0][0];
#pragma unroll
    for (int i = 0; i < 6; ++i) dst[tid + i * 256] = src[tid + i * 256];
  }
  __syncthreads();

  int lane = tid & 63, wv = tid >> 6;
  if (wv == 0) {
    int l = lane;
    int col = (l < 12) ? l : 11;           // in-bounds LDS column for all lanes
    int start = startp[0];
    float tr[12];
#pragma unroll
    for (int p = 0; p < 12; ++p) tr[p] = (l < 12) ? trans[l * 12 + p] : NEGV;
    float fv = (l == start) ? 0.f : NEGV;

    float feat = feat_s[1][col];
    for (int t = 1; t < NT; ++t) {
      float fnext = (t + 1 < NT) ? feat_s[t + 1][col] : 0.f;  // prefetch
      float v[12];
#pragma unroll
      for (int p = 0; p < 12; ++p) v[p] = rdlanef(fv, p) + tr[p];
      // first-max argmax tree (depth 4); left-wins-on->= keeps lowest index
      float m[6]; int mi[6];
#pragma unroll
      for (int k = 0; k < 6; ++k) {
        bool tk = v[2 * k] >= v[2 * k + 1];
        m[k] = tk ? v[2 * k] : v[2 * k + 1];
        mi[k] = tk ? (2 * k) : (2 * k + 1);
      }
      bool t0 = m[0] >= m[1];
      float a0 = t0 ? m[0] : m[1]; int ai0 = t0 ? mi[0] : mi[1];
      bool t1 = m[2] >= m[3];
      float a1 = t1 ? m[2] : m[3]; int ai1 = t1 ? mi[2] : mi[3];
      bool t2 = m[4] >= m[5];
      float a2 = t2 ? m[4] : m[5]; int ai2 = t2 ? mi[4] : mi[5];
      bool t3 = a0 >= a1;
      float b0 = t3 ? a0 : a1; int bi0 = t3 ? ai0 : ai1;
      bool t4 = b0 >= a2;
      float best = t4 ? b0 : a2; int bp = t4 ? bi0 : ai2;
      fv = best + feat;
      if (l < 12) ptr_s[t - 1][l] = (unsigned char)bp;
      feat = fnext;
    }

    // final score / last state: first-max over lanes<12
    float bvv = (l < 12) ? fv : -3.4e38f;
    int bii = l;
#pragma unroll
    for (int off = 32; off > 0; off >>= 1) {
      float v2 = __shfl_xor(bvv, off); int i2 = __shfl_xor(bii, off);
      if (v2 > bvv || (v2 == bvv && i2 < bii)) { bvv = v2; bii = i2; }
    }
    if (lane == 0) { outp[b] = bvv; path_s[NT - 1] = bii; }

    // backtrace: lane l holds ptr row; one uniform readlane per step
    int nxt = bii;
    int pb = (int)ptr_s[NT - 2][col];
    for (int t = NT - 2; t >= 0; --t) {
      int pbn = (t > 0) ? (int)ptr_s[t - 1][col] : 0;  // prefetch
      nxt = __builtin_amdgcn_readlane(pb, nxt);
      if (lane == 0) path_s[t] = nxt;
      pb = pbn;
    }
  }
  __syncthreads();

  // coalesced path write-out
#pragma unroll
  for (int i = 0; i < 2; ++i)
    outp[64 + (size_t)b * NT + tid + i * 256] = (float)path_s[tid + i * 256];
}

// ---- launch -----------------------------------------------------------------
extern "C" void kernel_launch(void* const* d_in, const int* in_sizes, int n_in,
                              void* d_out, int out_size, void* d_ws, size_t ws_size,
                              hipStream_t stream) {
  const float* X     = (const float*)d_in[0];
  const float* h0    = (const float*)d_in[1];
  const float* c0    = (const float*)d_in[2];
  const float* wihf  = (const float*)d_in[3];
  const float* whhf  = (const float*)d_in[4];
  const float* bihf  = (const float*)d_in[5];
  const float* bhhf  = (const float*)d_in[6];
  const float* wihb  = (const float*)d_in[7];
  const float* whhb  = (const float*)d_in[8];
  const float* bihb  = (const float*)d_in[9];
  const float* bhhb  = (const float*)d_in[10];
  const float* fcw   = (const float*)d_in[11];
  const float* fcb   = (const float*)d_in[12];
  const float* trans = (const float*)d_in[13];
  const int* startp  = (const int*)d_in[14];
  float* outp = (float*)d_out;
  char* ws = (char*)d_ws;

  // workspace layout (total ~77.5 MB)
  float* bias2 = (float*)(ws + 0);                       //     12,288
  u16* hraw    = (u16*)(ws + 12288);                     //    196,608 (4 slots)
  float* cbuf  = (float*)(ws + 208896);                  //    196,608
  u32* flags   = (u32*)(ws + 405504);                    //        128
  u32* claim   = (u32*)(ws + 405632);                    //        128
  u16* XPc     = (u16*)(ws + 409600);                    // 25,165,824 (2 bufs)
  u16* LOUT    = (u16*)(ws + 25575424);                  // 50,331,648
  float* em    = (float*)(ws + 75907072);                //  1,572,864

  prep_kernel<<<192, 256, 0, stream>>>(bihf, bhhf, bihb, bhhb, h0, c0,
                                       bias2, hraw, cbuf, flags, claim);
  gemm_xp0<<<dim3(24, 16), 256, 0, stream>>>(X, wihf, wihb, bias2, XPc);
  for (int p = 0; p < NPH; ++p) {
    fused_rec<<<1024, 256, 0, stream>>>(whhf, whhb, X, wihf, wihb, bias2,
                                        XPc, hraw, cbuf, LOUT, flags, claim, p);
  }
  fc_em<<<128, 256, 0, stream>>>(LOUT, fcw, fcb, em);
  viterbi_k<<<64, 256, 0, stream>>>(em, trans, startp, outp);
}

// Round 8
// 1850.581 us; speedup vs baseline: 1.9907x; 1.9907x over previous
//
#include <hip/hip_runtime.h>
#include <hip/hip_bf16.h>
#include <stdint.h>

// BertBiLstmCrf: B=64 T=512 H=768 LH=384 L=12
// prep -> gemm_xp0 -> fused_rec(p) x16 -> fc_em -> viterbi
// fused_rec(p): lstm phase p on XCD0 (dir0) + XCD1 (dir1), 24 workers each;
// gemm phase p+1 on XCD2-7 as 192 workers x 2 tiles.
// lstm v8: worker = (dir, batch-group of 32, j-slice of 32). W slice is only
// 96KB -> LDS-resident per phase (R6-validated XOR swizzle). h exchange is
// group-local (12 workers, same XCD L2). Waves specialize by GATE: wave g
// computes gate g for 32b x 32j; partials exchanged via swizzled gx LDS.
// Per-CU per-step LDS streaming drops 288KB -> ~125KB; h stage 48KB -> 24KB.
// LDS: hA 24,576 + hxch 2,048 + wlds 98,304 + gx 16,384 = 141,312 B (1 WG/CU).

#define NB 64
#define NT 512
#define NH 768
#define NLH 384
#define NPH 16
#define PS 32
#define NEGV -1000.0f

typedef __attribute__((ext_vector_type(4))) float f32x4;
typedef __attribute__((ext_vector_type(8))) short bf16x8;
typedef __attribute__((ext_vector_type(4))) unsigned int u32x4;
typedef unsigned short u16;
typedef unsigned int u32;

#define PSLOT ((size_t)PS * 3072 * 64)   // u16 elements per XPc phase buffer

__device__ __forceinline__ u16 f2bf(float f) {
  __hip_bfloat16 h = __float2bfloat16(f);
  return *reinterpret_cast<u16*>(&h);
}
__device__ __forceinline__ float bf2f(u16 u) {
  union { u32 i; float f; } v; v.i = ((u32)u) << 16; return v.f;
}
__device__ __forceinline__ u32 pack2(float a, float b) {
  return (u32)f2bf(a) | ((u32)f2bf(b) << 16);
}
__device__ __forceinline__ float bfx(uint2 v, int r) {
  u32 w = (r & 2) ? v.y : v.x;
  u16 h = (r & 1) ? (u16)(w >> 16) : (u16)(w & 0xffff);
  return bf2f(h);
}
__device__ __forceinline__ float sigm(float x) {
  x = fminf(fmaxf(x, -60.f), 60.f);
  return 1.0f / (1.0f + __expf(-x));
}
__device__ __forceinline__ float tanh_(float x) {
  x = fminf(fmaxf(x, -30.f), 30.f);
  return 2.0f / (1.0f + __expf(-2.0f * x)) - 1.0f;
}
__device__ __forceinline__ int xcc_id() {
  u32 v;
  asm volatile("s_getreg_b32 %0, hwreg(HW_REG_XCC_ID)" : "=s"(v));
  return (int)v;
}
__device__ __forceinline__ float rdlanef(float v, int lane) {
  union { float f; int i; } u; u.f = v;
  int r = __builtin_amdgcn_readlane(u.i, lane);
  union { int i; float f; } o; o.i = r; return o.f;
}

struct GemmSmem { u16 As[128][40]; u16 Bs[128][40]; };            //  20,480 B
struct LstmSmem {
  __align__(16) u16 hA[32 * 384];      // h_{t-1} [32b][384k] swz  24,576 B
  __align__(16) u16 hxch[32][32];      // h_t repack [b][jloc]      2,048 B
  __align__(16) u16 wlds[4 * 32 * 384];// W slice [g][32j][384k] swz 98,304 B
  __align__(16) float gx[4 * 32 * 32]; // gate partials [g][j][b] swz 16,384 B
};
union SmemU { GemmSmem g; LstmSmem l; };

// ---- prep ------------------------------------------------------------------
__global__ __launch_bounds__(256) void prep_kernel(
    const float* bihf, const float* bhhf, const float* bihb, const float* bhhb,
    const float* h0, const float* c0, float* bias2, u16* hraw, float* cbuf,
    u32* flags, u32* claim) {
  int t = blockIdx.x * 256 + threadIdx.x;
  if (t < 1536) bias2[t] = bihf[t] + bhhf[t];
  else if (t < 3072) bias2[t] = bihb[t - 1536] + bhhb[t - 1536];
  if (t < 64) flags[t] = 0;                       // 48 used
  if (t < 64) claim[t] = 0;                       // 32 lstm + 16 gemm
  if (t < 2 * NB * NLH) {
    hraw[t] = f2bf(h0[t]);   // slots 0,1 = dir 0,1 (parity 0), layout [b][j]
    int dir = t / 24576, r2 = t % 24576;
    int j = r2 / 64, b = r2 % 64;
    cbuf[t] = c0[(size_t)(dir * 64 + b) * 384 + j];  // cbuf[dir][j][b]
  }
}

// ---- gemm tile (device): XPout[(sl*3072 + n)*64 + b] for one 128x128 tile --
__device__ __forceinline__ void gemm_tile_dev(
    const float* __restrict__ A, const float* __restrict__ Wf,
    const float* __restrict__ Wb, const float* __restrict__ bias2,
    u16* __restrict__ XPout, int phaseG, int nb, int mb, GemmSmem& sm,
    int tid) {
  int dir = (nb >= 12) ? 1 : 0;
  const float* Bm = dir ? Wb : Wf;
  int n0g = nb * 128;
  int n0 = n0g - dir * 1536;
  int m0 = mb * 128;
  int tf0 = PS * phaseG, tb0 = (NT - 1) - PS * phaseG;
  int lane = tid & 63, wv = tid >> 6;
  int wm = (wv >> 1) * 64, wn = (wv & 1) * 64;
  int qr = lane & 15, qk8 = (lane >> 4) * 8, qm = (lane >> 4) * 4;

  f32x4 acc[4][4] = {};
  for (int kk = 0; kk < 768; kk += 32) {
    __syncthreads();
#pragma unroll
    for (int u = 0; u < 4; ++u) {
      int c = tid + u * 256;
      int row = c >> 3, q4 = (c & 7) * 4;
      int m = m0 + row;
      int sloc = m >> 6, b = m & 63;
      int t = dir ? (tb0 - sloc) : (tf0 + sloc);
      float4 av = *(const float4*)&A[(size_t)(b * NT + t) * 768 + kk + q4];
      float4 bv = *(const float4*)&Bm[(size_t)(n0 + row) * 768 + kk + q4];
      uint2 ap; ap.x = pack2(av.x, av.y); ap.y = pack2(av.z, av.w);
      uint2 bp; bp.x = pack2(bv.x, bv.y); bp.y = pack2(bv.z, bv.w);
      *(uint2*)&sm.As[row][q4] = ap;
      *(uint2*)&sm.Bs[row][q4] = bp;
    }
    __syncthreads();
    bf16x8 af[4], bfr[4];
#pragma unroll
    for (int i = 0; i < 4; ++i) af[i] = *(const bf16x8*)&sm.As[wm + i * 16 + qr][qk8];
#pragma unroll
    for (int j = 0; j < 4; ++j) bfr[j] = *(const bf16x8*)&sm.Bs[wn + j * 16 + qr][qk8];
#pragma unroll
    for (int i = 0; i < 4; ++i)
#pragma unroll
      for (int j = 0; j < 4; ++j)
        acc[i][j] = __builtin_amdgcn_mfma_f32_16x16x32_bf16(af[i], bfr[j], acc[i][j], 0, 0, 0);
  }
#pragma unroll
  for (int j = 0; j < 4; ++j) {
    int n = n0g + wn + j * 16 + qr;
    float bv = bias2[n];
#pragma unroll
    for (int i = 0; i < 4; ++i) {
      int mrel = wm + i * 16 + qm;           // 0..124 (r adds 0..3)
      int b0 = mrel & 63;
      int sl = mb * 2 + (mrel >> 6);         // 0..31
      uint2 pk;
      pk.x = pack2(acc[i][j][0] + bv, acc[i][j][1] + bv);
      pk.y = pack2(acc[i][j][2] + bv, acc[i][j][3] + bv);
      *(uint2*)&XPout[((size_t)sl * 3072 + n) * 64 + b0] = pk;
    }
  }
}

// ---- gemm_xp0: standalone gemm for phase 0 ----------------------------------
__global__ __launch_bounds__(256) void gemm_xp0(
    const float* __restrict__ A, const float* __restrict__ Wf,
    const float* __restrict__ Wb, const float* __restrict__ bias2,
    u16* __restrict__ XPc) {
  __shared__ GemmSmem sm;
  gemm_tile_dev(A, Wf, Wb, bias2, XPc, 0, blockIdx.x, blockIdx.y, sm,
                threadIdx.x);
}

// ---- fused_rec: lstm phase p (XCD0/1) || gemm phase p+1 (XCD2-7) ------------
__global__ __launch_bounds__(256, 1) void fused_rec(
    const float* __restrict__ Whhf, const float* __restrict__ Whhb,
    const float* __restrict__ A, const float* __restrict__ Wihf,
    const float* __restrict__ Wihb, const float* __restrict__ bias2,
    u16* __restrict__ XPc, u16* hraw, float* cbuf,
    u16* __restrict__ LOUT, u32* flags, u32* claim, int phase) {
  __shared__ SmemU sm;
  __shared__ int s_role;
  int tid = threadIdx.x;

  if (tid == 0) {
    int role = -1;
    int xcc = xcc_id();
    if (xcc < 2) {
      // XCD0 = dir0 workers, XCD1 = dir1 workers (group L2-local), or exit
      u32 r = __hip_atomic_fetch_add(&claim[phase * 2 + xcc], 1u,
                                     __ATOMIC_RELAXED, __HIP_MEMORY_SCOPE_AGENT);
      if (r < 24u) role = xcc * 24 + (int)r;      // 0..47 lstm
    } else if (phase + 1 < NPH) {
      u32 g = __hip_atomic_fetch_add(&claim[32 + phase], 1u,
                                     __ATOMIC_RELAXED, __HIP_MEMORY_SCOPE_AGENT);
      if (g < 192u) role = 48 + (int)g;           // gemm worker
    }
    s_role = role;
  }
  __syncthreads();
  int role = s_role;
  if (role < 0) return;

  if (role >= 48) {                               // ---- gemm role ----
    int g = role - 48;                            // 0..191
    u16* XPgemm = XPc + (size_t)((phase + 1) & 1) * PSLOT;
#pragma unroll 1
    for (int i = 0; i < 2; ++i) {                 // 2 tiles each
      int tile = g + 192 * i;                     // 0..383
      int nb = tile % 24, mb = tile / 24;         // 24 x 16 tiles
      gemm_tile_dev(A, Wihf, Wihb, bias2, XPgemm, phase + 1, nb, mb, sm.g, tid);
    }
    return;
  }

  // ---- lstm role ----
  auto& L = sm.l;
  const u16* __restrict__ XPlstm = XPc + (size_t)(phase & 1) * PSLOT;

  int dir = role / 24;
  int r2 = role % 24;
  int bg = r2 / 12, ns = r2 % 12;
  int gid = dir * 2 + bg;                   // flag group (12 workers)
  int lane = tid & 63, wv = tid >> 6;       // wv = GATE index 0..3
  int ll = lane & 15, q = lane >> 4;
  int q16 = q * 16;
  int xsw = (ll & 7) << 4;
  int jc = tid >> 3, bq = tid & 7;          // combine slot: j-col, b-quad
  int jg_c = ns * 32 + jc;
  const float* Whh = dir ? Whhb : Whhf;

  // stage W slice into LDS once per phase: [g][32j][384k] bf16, XOR-swizzled
#pragma unroll 1
  for (int it = 0; it < 24; ++it) {
    int cid = tid + it * 256;               // 0..6143 = 128 rows x 48 chunks
    int row = cid / 48, c16 = cid % 48;
    int g = row >> 5, j = row & 31;
    const float* wp = &Whh[(size_t)(g * 384 + ns * 32 + j) * 384 + c16 * 8];
    float4 w0 = *(const float4*)wp;
    float4 w1 = *(const float4*)(wp + 4);
    union { u32 u[4]; u32x4 v; } cv;
    cv.u[0] = pack2(w0.x, w0.y); cv.u[1] = pack2(w0.z, w0.w);
    cv.u[2] = pack2(w1.x, w1.y); cv.u[3] = pack2(w1.z, w1.w);
    *(u32x4*)((char*)L.wlds + row * 768 + ((c16 * 16) ^ ((j & 7) << 4))) = cv.v;
  }

  // persistent c state: thread owns (j=jc, b = bg*32 + bq*4 .. +3)
  f32x4 cst = *(const f32x4*)&cbuf[((size_t)dir * 384 + jg_c) * 64 + bg * 32 + bq * 4];

  int tf0 = PS * phase, tb0 = (NT - 1) - PS * phase;
  const size_t hslot = (size_t)NB * NLH;
  u32* myflag = &flags[gid * 12 + ns];

  for (int s = 0; s < PS; ++s) {
    int stepidx = phase * PS + s;
    int t = dir ? (tb0 - s) : (tf0 + s);
    int pp = s & 1;                         // PS even -> parity continues
    const u16* hsrc = hraw + (size_t)(pp * 2 + dir) * hslot;
    u16* hdst = hraw + (size_t)((pp ^ 1) * 2 + dir) * hslot;

    // XP prefetch (top-of-step; latency hides under stage+MFMA)
    uint2 xp[4];
    const u16* xpb = &XPlstm[((size_t)s * 3072 + dir * 1536 + jg_c) * 64 + bg * 32 + bq * 4];
#pragma unroll
    for (int g = 0; g < 4; ++g)
      xp[g] = *(const uint2*)&xpb[(size_t)g * 384 * 64];

    // stage h_{t-1} rows [bg*32..+32): 1536 x 16B nontemporal (L1-bypass)
#pragma unroll
    for (int it = 0; it < 6; ++it) {
      int cid = tid + it * 256;             // < 1536 = 32 rows x 48 chunks
      int row = cid / 48, c16 = cid % 48;
      u32x4 v = __builtin_nontemporal_load(
          (const u32x4*)&hsrc[(size_t)(bg * 32 + row) * 384 + c16 * 8]);
      *(u32x4*)((char*)L.hA + row * 768 + ((c16 * 16) ^ ((row & 7) << 4))) = v;
    }
    __syncthreads();

    // wave wv computes gate wv: 32b x 32j = 2 m-tiles x 2 n-tiles, K=384
    f32x4 acc00 = {}, acc01 = {}, acc10 = {}, acc11 = {};
#pragma unroll
    for (int kk = 0; kk < 12; ++kk) {
      int kb = kk * 64 + q16;
      bf16x8 a0 = *(const bf16x8*)((const char*)L.hA + ll * 768 + (kb ^ xsw));
      bf16x8 a1 = *(const bf16x8*)((const char*)L.hA + (16 + ll) * 768 + (kb ^ xsw));
      bf16x8 b0 = *(const bf16x8*)((const char*)L.wlds + (wv * 32 + ll) * 768 + (kb ^ xsw));
      bf16x8 b1 = *(const bf16x8*)((const char*)L.wlds + (wv * 32 + 16 + ll) * 768 + (kb ^ xsw));
      acc00 = __builtin_amdgcn_mfma_f32_16x16x32_bf16(a0, b0, acc00, 0, 0, 0);
      acc01 = __builtin_amdgcn_mfma_f32_16x16x32_bf16(a0, b1, acc01, 0, 0, 0);
      acc10 = __builtin_amdgcn_mfma_f32_16x16x32_bf16(a1, b0, acc10, 0, 0, 0);
      acc11 = __builtin_amdgcn_mfma_f32_16x16x32_bf16(a1, b1, acc11, 0, 0, 0);
    }
    // publish gate partials: gx[g][j][b] f32, b-offset XOR-swizzled by j
    {
      int rb0 = (wv * 32 + ll) * 128;       // n-tile 0 row (j = ll)
      int rb1 = (wv * 32 + 16 + ll) * 128;  // n-tile 1 row (j = 16+ll)
      *(f32x4*)((char*)L.gx + rb0 + ((q16) ^ xsw)) = acc00;        // mt0
      *(f32x4*)((char*)L.gx + rb0 + ((64 + q16) ^ xsw)) = acc10;   // mt1
      *(f32x4*)((char*)L.gx + rb1 + ((q16) ^ xsw)) = acc01;
      *(f32x4*)((char*)L.gx + rb1 + ((64 + q16) ^ xsw)) = acc11;
    }
    __syncthreads();

    // combine: thread (jc, bq) -> 4 outputs (b = bg*32 + bq*4 + r, j = jc)
    {
      int xswc = (jc & 7) << 4;
      f32x4 gv0 = *(const f32x4*)((const char*)L.gx + (0 * 32 + jc) * 128 + ((bq * 16) ^ xswc));
      f32x4 gv1 = *(const f32x4*)((const char*)L.gx + (1 * 32 + jc) * 128 + ((bq * 16) ^ xswc));
      f32x4 gv2 = *(const f32x4*)((const char*)L.gx + (2 * 32 + jc) * 128 + ((bq * 16) ^ xswc));
      f32x4 gv3 = *(const f32x4*)((const char*)L.gx + (3 * 32 + jc) * 128 + ((bq * 16) ^ xswc));
#pragma unroll
      for (int r = 0; r < 4; ++r) {
        float pi = gv0[r] + bfx(xp[0], r);
        float pf = gv1[r] + bfx(xp[1], r);
        float pg = gv2[r] + bfx(xp[2], r);
        float po = gv3[r] + bfx(xp[3], r);
        float ig = sigm(pi), fg = sigm(pf), gg = tanh_(pg), og = sigm(po);
        float cv = fg * cst[r] + ig * gg;
        cst[r] = cv;
        u16 hb = f2bf(og * tanh_(cv));
        L.hxch[bq * 4 + r][jc] = hb;
        LOUT[((size_t)(bg * 32 + bq * 4 + r) * NT + t) * 768 + dir * 384 + jg_c] = hb;
      }
    }
    __syncthreads();

    // publish h_t slice: 128 x 16B plain write-through stores -> own-XCD L2
    if (tid < 128) {
      int row = tid >> 2, seg = tid & 3;
      *(u32x4*)&hdst[(size_t)(bg * 32 + row) * 384 + ns * 32 + seg * 8] =
          *(const u32x4*)&L.hxch[row][seg * 8];
    }
    __syncthreads();  // vmcnt(0) drain: publish + LOUT in L2 before flag

    if (tid == 0)
      __hip_atomic_store(myflag, (u32)(stepidx + 1),
                         __ATOMIC_RELAXED, __HIP_MEMORY_SCOPE_WORKGROUP);
    if (wv == 0) {
      int spins = 0;
      while (true) {
        u32 v = 0xffffffffu;
        if (lane < 12)
          v = __builtin_nontemporal_load(&flags[gid * 12 + lane]);
        asm volatile("" ::: "memory");  // no CSE across poll iterations
        if (~__ballot(v > (u32)stepidx) == 0ull) break;
        __builtin_amdgcn_s_sleep(1);
        if (++spins > (1 << 14)) break;  // fail-fast liveness guard
      }
    }
    __syncthreads();
  }

  // persist c state
  *(f32x4*)&cbuf[((size_t)dir * 384 + jg_c) * 64 + bg * 32 + bq * 4] = cst;
}

// ---- fc_em: emissions = LOUT @ fc_w^T + fc_b --------------------------------
__global__ __launch_bounds__(256) void fc_em(
    const u16* __restrict__ LOUT, const float* __restrict__ fcw,
    const float* __restrict__ fcb, float* __restrict__ em) {
  __shared__ float wsm[12][768];
  __shared__ float wbv[12];
  int tid = threadIdx.x;
  for (int i = tid; i < 12 * 768; i += 256) wsm[i / 768][i % 768] = fcw[i];
  if (tid < 12) wbv[tid] = fcb[tid];
  __syncthreads();
  int lane = tid & 63, wv = tid >> 6;
  for (int r = blockIdx.x * 4 + wv; r < NB * NT; r += gridDim.x * 4) {
    float x[12];
#pragma unroll
    for (int c = 0; c < 12; ++c) x[c] = bf2f(LOUT[(size_t)r * 768 + c * 64 + lane]);
    float sums[12];
#pragma unroll
    for (int l = 0; l < 12; ++l) {
      float pv = 0.f;
#pragma unroll
      for (int c = 0; c < 12; ++c) pv += x[c] * wsm[l][c * 64 + lane];
#pragma unroll
      for (int off = 32; off > 0; off >>= 1) pv += __shfl_xor(pv, off);
      sums[l] = pv + wbv[l];
    }
    if (lane == 0) {
#pragma unroll
      for (int l = 0; l < 12; ++l) em[(size_t)r * 12 + l] = sums[l];
    }
  }
}

// ---- viterbi v2: one block per batch, fully LDS-resident --------------------
__global__ __launch_bounds__(256) void viterbi_k(
    const float* __restrict__ em, const float* __restrict__ trans,
    const int* __restrict__ startp, float* __restrict__ outp) {
  __shared__ __align__(16) float feat_s[NT][12];    // 24576 B
  __shared__ unsigned char ptr_s[NT][12];           // 6144 B (rows 0..510 used)
  __shared__ int path_s[NT];                        // 2048 B
  int tid = threadIdx.x;
  int b = blockIdx.x;

  {
    const float4* src = (const float4*)(em + (size_t)b * NT * 12);
    float4* dst = (float4*)&feat_s[0][0];
#pragma unroll
    for (int i = 0; i < 6; ++i) dst[tid + i * 256] = src[tid + i * 256];
  }
  __syncthreads();

  int lane = tid & 63, wv = tid >> 6;
  if (wv == 0) {
    int l = lane;
    int col = (l < 12) ? l : 11;
    int start = startp[0];
    float tr[12];
#pragma unroll
    for (int p = 0; p < 12; ++p) tr[p] = (l < 12) ? trans[l * 12 + p] : NEGV;
    float fv = (l == start) ? 0.f : NEGV;

    float feat = feat_s[1][col];
    for (int t = 1; t < NT; ++t) {
      float fnext = (t + 1 < NT) ? feat_s[t + 1][col] : 0.f;
      float v[12];
#pragma unroll
      for (int p = 0; p < 12; ++p) v[p] = rdlanef(fv, p) + tr[p];
      float m[6]; int mi[6];
#pragma unroll
      for (int k = 0; k < 6; ++k) {
        bool tk = v[2 * k] >= v[2 * k + 1];
        m[k] = tk ? v[2 * k] : v[2 * k + 1];
        mi[k] = tk ? (2 * k) : (2 * k + 1);
      }
      bool t0 = m[0] >= m[1];
      float a0 = t0 ? m[0] : m[1]; int ai0 = t0 ? mi[0] : mi[1];
      bool t1 = m[2] >= m[3];
      float a1 = t1 ? m[2] : m[3]; int ai1 = t1 ? mi[2] : mi[3];
      bool t2 = m[4] >= m[5];
      float a2 = t2 ? m[4] : m[5]; int ai2 = t2 ? mi[4] : mi[5];
      bool t3 = a0 >= a1;
      float b0 = t3 ? a0 : a1; int bi0 = t3 ? ai0 : ai1;
      bool t4 = b0 >= a2;
      float best = t4 ? b0 : a2; int bp = t4 ? bi0 : ai2;
      fv = best + feat;
      if (l < 12) ptr_s[t - 1][l] = (unsigned char)bp;
      feat = fnext;
    }

    float bvv = (l < 12) ? fv : -3.4e38f;
    int bii = l;
#pragma unroll
    for (int off = 32; off > 0; off >>= 1) {
      float v2 = __shfl_xor(bvv, off); int i2 = __shfl_xor(bii, off);
      if (v2 > bvv || (v2 == bvv && i2 < bii)) { bvv = v2; bii = i2; }
    }
    if (lane == 0) { outp[b] = bvv; path_s[NT - 1] = bii; }

    int nxt = bii;
    int pb = (int)ptr_s[NT - 2][col];
    for (int t = NT - 2; t >= 0; --t) {
      int pbn = (t > 0) ? (int)ptr_s[t - 1][col] : 0;
      nxt = __builtin_amdgcn_readlane(pb, nxt);
      if (lane == 0) path_s[t] = nxt;
      pb = pbn;
    }
  }
  __syncthreads();

#pragma unroll
  for (int i = 0; i < 2; ++i)
    outp[64 + (size_t)b * NT + tid + i * 256] = (float)path_s[tid + i * 256];
}

// ---- launch -----------------------------------------------------------------
extern "C" void kernel_launch(void* const* d_in, const int* in_sizes, int n_in,
                              void* d_out, int out_size, void* d_ws, size_t ws_size,
                              hipStream_t stream) {
  const float* X     = (const float*)d_in[0];
  const float* h0    = (const float*)d_in[1];
  const float* c0    = (const float*)d_in[2];
  const float* wihf  = (const float*)d_in[3];
  const float* whhf  = (const float*)d_in[4];
  const float* bihf  = (const float*)d_in[5];
  const float* bhhf  = (const float*)d_in[6];
  const float* wihb  = (const float*)d_in[7];
  const float* whhb  = (const float*)d_in[8];
  const float* bihb  = (const float*)d_in[9];
  const float* bhhb  = (const float*)d_in[10];
  const float* fcw   = (const float*)d_in[11];
  const float* fcb   = (const float*)d_in[12];
  const float* trans = (const float*)d_in[13];
  const int* startp  = (const int*)d_in[14];
  float* outp = (float*)d_out;
  char* ws = (char*)d_ws;

  // workspace layout (total ~77.5 MB)
  float* bias2 = (float*)(ws + 0);                       //     12,288
  u16* hraw    = (u16*)(ws + 12288);                     //    196,608 (4 slots)
  float* cbuf  = (float*)(ws + 208896);                  //    196,608
  u32* flags   = (u32*)(ws + 405504);                    //        256
  u32* claim   = (u32*)(ws + 405760);                    //        256
  u16* XPc     = (u16*)(ws + 409600);                    // 25,165,824 (2 bufs)
  u16* LOUT    = (u16*)(ws + 25575424);                  // 50,331,648
  float* em    = (float*)(ws + 75907072);                //  1,572,864

  prep_kernel<<<192, 256, 0, stream>>>(bihf, bhhf, bihb, bhhb, h0, c0,
                                       bias2, hraw, cbuf, flags, claim);
  gemm_xp0<<<dim3(24, 16), 256, 0, stream>>>(X, wihf, wihb, bias2, XPc);
  for (int p = 0; p < NPH; ++p) {
    fused_rec<<<1024, 256, 0, stream>>>(whhf, whhb, X, wihf, wihb, bias2,
                                        XPc, hraw, cbuf, LOUT, flags, claim, p);
  }
  fc_em<<<128, 256, 0, stream>>>(LOUT, fcw, fcb, em);
  viterbi_k<<<64, 256, 0, stream>>>(em, trans, startp, outp);
}